// Round 1
// baseline (171.335 us; speedup 1.0000x reference)
//
#include <hip/hip_runtime.h>

#define N_SRC_C   100000
#define N_DST_C   50000
#define N_EDGES_C 800000
#define D_C       64
// h_neigh = (1-ALPHA)*HBar + ALPHA*mean   (stop_gradient identity in fwd)
#define ONE_MINUS_ALPHA 0.9f
#define ALPHA_C        0.1f

// ---------------------------------------------------------------------------
// Kernel A: per-wave (64 lanes = 64 features) segment mean + control-variate
// blend. dst_idx is sorted -> binary search for this node's edge range.
// ---------------------------------------------------------------------------
__global__ __launch_bounds__(256) void sage_mean_kernel(
    const float* __restrict__ H_src,
    const float* __restrict__ HBar,
    const int*   __restrict__ src_idx,
    const int*   __restrict__ dst_idx,
    float*       __restrict__ h_neigh_out)  // [N_DST][64]
{
    const int wave = threadIdx.x >> 6;
    const int lane = threadIdx.x & 63;
    const int d = blockIdx.x * 4 + wave;
    if (d >= N_DST_C) return;

    // lower_bound(d): first edge with dst >= d   (wave-uniform search)
    int lo = 0, hi = N_EDGES_C;
    while (lo < hi) { int m = (lo + hi) >> 1; if (dst_idx[m] < d) lo = m + 1; else hi = m; }
    const int seg_begin = lo;
    // upper_bound(d): first edge with dst > d
    hi = N_EDGES_C;
    while (lo < hi) { int m = (lo + hi) >> 1; if (dst_idx[m] <= d) lo = m + 1; else hi = m; }
    const int seg_end = lo;

    float a0 = 0.f, a1 = 0.f, a2 = 0.f, a3 = 0.f;
    int e = seg_begin;
    for (; e + 4 <= seg_end; e += 4) {
        const int i0 = src_idx[e + 0];
        const int i1 = src_idx[e + 1];
        const int i2 = src_idx[e + 2];
        const int i3 = src_idx[e + 3];
        a0 += H_src[i0 * D_C + lane];
        a1 += H_src[i1 * D_C + lane];
        a2 += H_src[i2 * D_C + lane];
        a3 += H_src[i3 * D_C + lane];
    }
    for (; e < seg_end; ++e) {
        a0 += H_src[src_idx[e] * D_C + lane];
    }
    const float sum = (a0 + a1) + (a2 + a3);
    const int cnt = seg_end - seg_begin;
    const float mean = (cnt > 0) ? (sum / (float)cnt) : 0.0f;

    const float hb = HBar[d * D_C + lane];
    h_neigh_out[d * D_C + lane] = ONE_MINUS_ALPHA * hb + ALPHA_C * mean;
}

// ---------------------------------------------------------------------------
// Kernel B: one thread per dst node. x-row (128 f32) lives in registers;
// W (64x128) + b staged in LDS, read with wave-uniform float4 broadcasts
// (conflict-free). 4 partial accumulators break the FMA dependence chain.
// ---------------------------------------------------------------------------
__global__ __launch_bounds__(256) void sage_linear_kernel(
    const float* __restrict__ H_dst,
    const float* __restrict__ h_neigh,   // output of kernel A
    const float* __restrict__ W,         // [64][128], row o = output feature
    const float* __restrict__ b,         // [64]
    float*       __restrict__ h_out)     // [N_DST][64]
{
    __shared__ __align__(16) float Ws[64 * 128];
    __shared__ float bs[64];

    for (int i = threadIdx.x; i < 64 * 128; i += 256) Ws[i] = W[i];
    if (threadIdx.x < 64) bs[threadIdx.x] = b[threadIdx.x];
    __syncthreads();

    const int node = blockIdx.x * 256 + threadIdx.x;
    if (node >= N_DST_C) return;

    // Load x = [H_dst row | h_neigh row] into registers (fully unrolled ->
    // static indices -> stays in VGPRs, no scratch).
    float x[128];
    #pragma unroll
    for (int k4 = 0; k4 < 16; ++k4) {
        const float4 v = *reinterpret_cast<const float4*>(&H_dst[node * 64 + k4 * 4]);
        x[k4 * 4 + 0] = v.x; x[k4 * 4 + 1] = v.y;
        x[k4 * 4 + 2] = v.z; x[k4 * 4 + 3] = v.w;
    }
    #pragma unroll
    for (int k4 = 0; k4 < 16; ++k4) {
        const float4 v = *reinterpret_cast<const float4*>(&h_neigh[node * 64 + k4 * 4]);
        x[64 + k4 * 4 + 0] = v.x; x[64 + k4 * 4 + 1] = v.y;
        x[64 + k4 * 4 + 2] = v.z; x[64 + k4 * 4 + 3] = v.w;
    }

    for (int o = 0; o < 64; ++o) {
        float p0 = 0.f, p1 = 0.f, p2 = 0.f, p3 = 0.f;
        #pragma unroll
        for (int k4 = 0; k4 < 32; ++k4) {
            const float4 w = *reinterpret_cast<const float4*>(&Ws[o * 128 + k4 * 4]);
            p0 += w.x * x[k4 * 4 + 0];
            p1 += w.y * x[k4 * 4 + 1];
            p2 += w.z * x[k4 * 4 + 2];
            p3 += w.w * x[k4 * 4 + 3];
        }
        const float acc = bs[o] + ((p0 + p1) + (p2 + p3));
        h_out[node * 64 + o] = fmaxf(acc, 0.0f);
    }
}

// ---------------------------------------------------------------------------
extern "C" void kernel_launch(void* const* d_in, const int* in_sizes, int n_in,
                              void* d_out, int out_size, void* d_ws, size_t ws_size,
                              hipStream_t stream) {
    const float* H_src   = (const float*)d_in[0];
    const float* H_dst   = (const float*)d_in[1];
    const float* HBar    = (const float*)d_in[2];
    const int*   src_idx = (const int*)d_in[3];
    const int*   dst_idx = (const int*)d_in[4];
    const float* W       = (const float*)d_in[5];
    const float* b       = (const float*)d_in[6];

    float* out     = (float*)d_out;
    float* h_out   = out;                            // [N_DST][64]
    float* hn_out  = out + (size_t)N_DST_C * D_C;    // [N_DST][64]

    // Kernel A: 4 waves/block, one wave per node -> 12500 blocks exactly.
    hipLaunchKernelGGL(sage_mean_kernel, dim3(N_DST_C / 4), dim3(256), 0, stream,
                       H_src, HBar, src_idx, dst_idx, hn_out);

    // Kernel B: one thread per node.
    hipLaunchKernelGGL(sage_linear_kernel, dim3((N_DST_C + 255) / 256), dim3(256), 0, stream,
                       H_dst, hn_out, W, b, h_out);
}

// Round 2
// 86.317 us; speedup vs baseline: 1.9850x; 1.9850x over previous
//
#include <hip/hip_runtime.h>

#define N_SRC_C   100000
#define N_DST_C   50000
#define N_EDGES_C 800000
#define D_C       64
// h_neigh = (1-ALPHA)*HBar + ALPHA*mean   (stop_gradient identity in fwd)
#define ONE_MINUS_ALPHA 0.9f
#define ALPHA_C        0.1f

// ---------------------------------------------------------------------------
// Kernel 0: CSR row_ptr build from the sorted dst_idx.
// row_ptr[n] = first edge e with dst_idx[e] >= n; row_ptr[N_DST] = E.
// Thread e fills all boundaries in (dst_idx[e-1], dst_idx[e]]; gaps are tiny
// (Poisson-16 degrees), the loop almost always runs 0 or 1 iterations.
// ---------------------------------------------------------------------------
__global__ __launch_bounds__(256) void build_rowptr_kernel(
    const int* __restrict__ dst_idx, int* __restrict__ row_ptr)
{
    const int e = blockIdx.x * 256 + threadIdx.x;
    if (e >= N_EDGES_C) return;
    const int d = dst_idx[e];
    const int p = (e == 0) ? -1 : dst_idx[e - 1];
    for (int n = p + 1; n <= d; ++n) row_ptr[n] = e;
    if (e == N_EDGES_C - 1) {
        for (int n = d + 1; n <= N_DST_C; ++n) row_ptr[n] = N_EDGES_C;
    }
}

// ---------------------------------------------------------------------------
// Kernel A: per-wave (64 lanes = 64 features) segment mean + CV blend.
// Segment bounds come from row_ptr (2 loads, replaces 34-load binary search).
// 8 independent accumulators keep 8 gather rows in flight.
// ---------------------------------------------------------------------------
__global__ __launch_bounds__(256) void sage_mean_kernel(
    const float* __restrict__ H_src,
    const float* __restrict__ HBar,
    const int*   __restrict__ src_idx,
    const int*   __restrict__ row_ptr,
    float*       __restrict__ h_neigh_out)  // [N_DST][64]
{
    const int wave = threadIdx.x >> 6;
    const int lane = threadIdx.x & 63;
    const int d = blockIdx.x * 4 + wave;
    if (d >= N_DST_C) return;

    const int seg_begin = row_ptr[d];
    const int seg_end   = row_ptr[d + 1];

    float a0 = 0.f, a1 = 0.f, a2 = 0.f, a3 = 0.f;
    float a4 = 0.f, a5 = 0.f, a6 = 0.f, a7 = 0.f;
    int e = seg_begin;
    for (; e + 8 <= seg_end; e += 8) {
        const int i0 = src_idx[e + 0];
        const int i1 = src_idx[e + 1];
        const int i2 = src_idx[e + 2];
        const int i3 = src_idx[e + 3];
        const int i4 = src_idx[e + 4];
        const int i5 = src_idx[e + 5];
        const int i6 = src_idx[e + 6];
        const int i7 = src_idx[e + 7];
        a0 += H_src[i0 * D_C + lane];
        a1 += H_src[i1 * D_C + lane];
        a2 += H_src[i2 * D_C + lane];
        a3 += H_src[i3 * D_C + lane];
        a4 += H_src[i4 * D_C + lane];
        a5 += H_src[i5 * D_C + lane];
        a6 += H_src[i6 * D_C + lane];
        a7 += H_src[i7 * D_C + lane];
    }
    for (; e + 4 <= seg_end; e += 4) {
        const int i0 = src_idx[e + 0];
        const int i1 = src_idx[e + 1];
        const int i2 = src_idx[e + 2];
        const int i3 = src_idx[e + 3];
        a0 += H_src[i0 * D_C + lane];
        a1 += H_src[i1 * D_C + lane];
        a2 += H_src[i2 * D_C + lane];
        a3 += H_src[i3 * D_C + lane];
    }
    for (; e < seg_end; ++e) {
        a0 += H_src[src_idx[e] * D_C + lane];
    }
    const float sum = ((a0 + a1) + (a2 + a3)) + ((a4 + a5) + (a6 + a7));
    const int cnt = seg_end - seg_begin;
    const float mean = (cnt > 0) ? (sum / (float)cnt) : 0.0f;

    const float hb = HBar[d * D_C + lane];
    h_neigh_out[d * D_C + lane] = ONE_MINUS_ALPHA * hb + ALPHA_C * mean;
}

// ---------------------------------------------------------------------------
// Kernel B: 64 nodes per block; 4 waves each compute a 16-output quarter of
// every node. node = tid&63 (lane), q = tid>>6 (wave) ->
//  - W reads from LDS are wave-uniform broadcasts (conflict-free)
//  - x-row global loads are lane-distinct (coalesced 16B/lane)
//  - 3128 waves total (vs 782 for 1-thread/node) -> real latency hiding
// ---------------------------------------------------------------------------
__global__ __launch_bounds__(256) void sage_linear_kernel(
    const float* __restrict__ H_dst,
    const float* __restrict__ h_neigh,   // output of kernel A
    const float* __restrict__ W,         // [64][128]
    const float* __restrict__ b,         // [64]
    float*       __restrict__ h_out)     // [N_DST][64]
{
    __shared__ __align__(16) float Ws[64 * 128];
    __shared__ float bs[64];

    for (int i = threadIdx.x; i < 64 * 128; i += 256) Ws[i] = W[i];
    if (threadIdx.x < 64) bs[threadIdx.x] = b[threadIdx.x];
    __syncthreads();

    const int node = blockIdx.x * 64 + (threadIdx.x & 63);
    const int q    = threadIdx.x >> 6;          // output quarter 0..3
    if (node >= N_DST_C) return;

    // x = [H_dst row | h_neigh row] in registers (static indices -> VGPRs)
    float x[128];
    #pragma unroll
    for (int k4 = 0; k4 < 16; ++k4) {
        const float4 v = *reinterpret_cast<const float4*>(&H_dst[node * 64 + k4 * 4]);
        x[k4 * 4 + 0] = v.x; x[k4 * 4 + 1] = v.y;
        x[k4 * 4 + 2] = v.z; x[k4 * 4 + 3] = v.w;
    }
    #pragma unroll
    for (int k4 = 0; k4 < 16; ++k4) {
        const float4 v = *reinterpret_cast<const float4*>(&h_neigh[node * 64 + k4 * 4]);
        x[64 + k4 * 4 + 0] = v.x; x[64 + k4 * 4 + 1] = v.y;
        x[64 + k4 * 4 + 2] = v.z; x[64 + k4 * 4 + 3] = v.w;
    }

    float acc[16];
    #pragma unroll
    for (int oo = 0; oo < 16; ++oo) {
        const int o = q * 16 + oo;
        float p0 = 0.f, p1 = 0.f, p2 = 0.f, p3 = 0.f;
        #pragma unroll
        for (int k4 = 0; k4 < 32; ++k4) {
            const float4 w = *reinterpret_cast<const float4*>(&Ws[o * 128 + k4 * 4]);
            p0 += w.x * x[k4 * 4 + 0];
            p1 += w.y * x[k4 * 4 + 1];
            p2 += w.z * x[k4 * 4 + 2];
            p3 += w.w * x[k4 * 4 + 3];
        }
        acc[oo] = fmaxf(bs[o] + ((p0 + p1) + (p2 + p3)), 0.0f);
    }

    // 16 contiguous outputs per thread -> 4 float4 stores
    #pragma unroll
    for (int oo4 = 0; oo4 < 4; ++oo4) {
        float4 v;
        v.x = acc[oo4 * 4 + 0]; v.y = acc[oo4 * 4 + 1];
        v.z = acc[oo4 * 4 + 2]; v.w = acc[oo4 * 4 + 3];
        *reinterpret_cast<float4*>(&h_out[node * 64 + q * 16 + oo4 * 4]) = v;
    }
}

// ---------------------------------------------------------------------------
extern "C" void kernel_launch(void* const* d_in, const int* in_sizes, int n_in,
                              void* d_out, int out_size, void* d_ws, size_t ws_size,
                              hipStream_t stream) {
    const float* H_src   = (const float*)d_in[0];
    const float* H_dst   = (const float*)d_in[1];
    const float* HBar    = (const float*)d_in[2];
    const int*   src_idx = (const int*)d_in[3];
    const int*   dst_idx = (const int*)d_in[4];
    const float* W       = (const float*)d_in[5];
    const float* b       = (const float*)d_in[6];

    float* out     = (float*)d_out;
    float* h_out   = out;                            // [N_DST][64]
    float* hn_out  = out + (size_t)N_DST_C * D_C;    // [N_DST][64]

    int* row_ptr = (int*)d_ws;                       // (N_DST+1) ints = 200 KB

    hipLaunchKernelGGL(build_rowptr_kernel, dim3((N_EDGES_C + 255) / 256), dim3(256), 0, stream,
                       dst_idx, row_ptr);

    hipLaunchKernelGGL(sage_mean_kernel, dim3(N_DST_C / 4), dim3(256), 0, stream,
                       H_src, HBar, src_idx, row_ptr, hn_out);

    hipLaunchKernelGGL(sage_linear_kernel, dim3((N_DST_C + 63) / 64), dim3(256), 0, stream,
                       H_dst, hn_out, W, b, h_out);
}